// Round 3
// baseline (170.827 us; speedup 1.0000x reference)
//
#include <hip/hip_runtime.h>

namespace {

constexpr int T_STEPS = 1024;
constexpr int BATCH   = 16;
constexpr int NNEUR   = 2048;
constexpr int MCOLS   = 512;
constexpr int BN      = BATCH * NNEUR;   // 32768

constexpr double DT_D   = 1e-7;
constexpr double TAU_D  = 1e-4;

constexpr float DT_F     = 1e-7f;
constexpr float CMEM_F   = 1e-12f;
constexpr float GLEAK_F  = 1e-9f;
constexpr float VTH_F    = 0.7f;             // VTH * GAIN
constexpr float REFRAC_F = 1e-6f;
constexpr float AINC_F   = 5e-11f;
constexpr float DECAY_F  = (float)(1.0 - DT_D / TAU_D);   // 0.999f
constexpr float VRESET_F = 0.0f;

// LIF staging geometry: 256 neurons per block, 4 waves.
constexpr int NPB     = 256;                  // neurons per block
constexpr int C_STEPS = 8;                    // timesteps per LDS buffer
constexpr int NBUF    = T_STEPS / C_STEPS;    // 128
constexpr int RING    = 6;                    // LDS ring depth (144 KB)
constexpr int AHEAD   = 5;                    // prefetch distance (buffers)
constexpr int LPB_W   = 6;                    // loads per buffer per wave (24 total / 4 waves)

} // namespace

// One LIF step, byte-identical numerics to the round-1/2 passing kernels.
#define LIF_STEP(ec, ic, vc, tidx)                                         \
    do {                                                                   \
        float t      = (float)(tidx) * DT_F;                               \
        bool  active = (t - ls) >= REFRAC_F;                               \
        float totI   = ((ec) - A) + (ic);                                  \
        float Vn     = (V + (DT_F * (totI - GLEAK_F * V)) / CMEM_F) + (vc);\
        float An     = A * DECAY_F;                                        \
        float V1     = active ? Vn : V;                                    \
        float A1     = active ? An : A;                                    \
        bool  spike  = active && (V1 >= VTH_F);                            \
        V  = spike ? VRESET_F : V1;                                        \
        A  = spike ? (A1 + AINC_F) : A1;                                   \
        ls = spike ? t : ls;                                               \
        count += spike ? 1 : 0;                                            \
    } while (0)

// 128 blocks x 4 waves. Each global_load_lds covers ONE timestep x 256
// consecutive neurons = 1 KB fully contiguous. Wave w issues its own 6
// loads per buffer (private vmcnt), all waves consume after a raw s_barrier.
__global__ __launch_bounds__(256) void lif_sim_kernel(
    const float* __restrict__ ext,
    const float* __restrict__ inz,
    const float* __restrict__ vnz,
    float* __restrict__ rates)
{
    // [slot][array][t within buffer][neuron] : 6*3*8*256*4 = 144 KB
    __shared__ float smem[RING][3][C_STEPS][NPB];

    const int tid  = threadIdx.x;
    const int lane = tid & 63;
    const int w    = tid >> 6;          // wave 0..3
    const int n0   = blockIdx.x * NPB;

    // wave w's load list: li = w*6 + l, a = li % 3, tt = li / 3
    auto issue = [&](int j) {
        const int slot = j % RING;
#pragma unroll
        for (int l = 0; l < LPB_W; ++l) {
            const int li = w * LPB_W + l;
            const int a  = li % 3;
            const int tt = li / 3;
            const float* base = (a == 0) ? ext : ((a == 1) ? inz : vnz);
            // lane supplies addr of 4 consecutive floats; LDS dst = base + lane*16
            const float* gp = base + (size_t)(j * C_STEPS + tt) * BN + (n0 + lane * 4);
            __builtin_amdgcn_global_load_lds(
                (const __attribute__((address_space(1))) void*)gp,
                (__attribute__((address_space(3))) void*)&smem[slot][a][tt][0],
                16, 0, 0);
        }
    };

    float V = 0.0f, A = 0.0f, ls = -1e9f;
    int count = 0;

    // prologue: fill pipe with buffers 0..AHEAD-1
    for (int j = 0; j < AHEAD; ++j) issue(j);

    for (int k = 0; k < NBUF; ++k) {
        // wave-private wait: outstanding buffers beyond k = min(AHEAD-1, NBUF-1-k)
        const int rem = NBUF - 1 - k;
        const int nb  = (rem < AHEAD - 1) ? rem : (AHEAD - 1);
        switch (nb) {
            case 4: asm volatile("s_waitcnt vmcnt(24)" ::: "memory"); break;
            case 3: asm volatile("s_waitcnt vmcnt(18)" ::: "memory"); break;
            case 2: asm volatile("s_waitcnt vmcnt(12)" ::: "memory"); break;
            case 1: asm volatile("s_waitcnt vmcnt(6)"  ::: "memory"); break;
            default: asm volatile("s_waitcnt vmcnt(0)" ::: "memory"); break;
        }
        // raw barrier (NOT __syncthreads: that would drain vmcnt(0) and
        // collapse the pipeline). sched_barrier pins ordering (rule #18).
        __builtin_amdgcn_s_barrier();
        __builtin_amdgcn_sched_barrier(0);

        // issue k+AHEAD into slot (k+AHEAD)%RING = buffer (k-1)'s slot; safe:
        // all waves finished reading buffer k-1 before barrier k above.
        if (k + AHEAD < NBUF) issue(k + AHEAD);

        const int slot = k % RING;
#pragma unroll
        for (int c = 0; c < C_STEPS; ++c) {
            float ec = smem[slot][0][c][w * 64 + lane];
            float ic = smem[slot][1][c][w * 64 + lane];
            float vc = smem[slot][2][c][w * 64 + lane];
            LIF_STEP(ec, ic, vc, k * C_STEPS + c);
        }
    }

    rates[n0 + tid] = (float)count * (1.0f / 1024.0f);
}

// ---------------- readout: rates[16,2048] @ (Gn*0.1)[2048,512] ----------------
constexpr int KC   = 8;
constexpr int KCH  = NNEUR / KC;    // 256 k per chunk
constexpr int KSUB = 4;             // waves per block splitting the chunk
constexpr int KPT  = KCH / KSUB;    // 64 k per thread

__global__ __launch_bounds__(256) void readout_partial_kernel(
    const float* __restrict__ rates,
    const float* __restrict__ G,
    const float* __restrict__ cn,
    float* __restrict__ part)
{
    __shared__ float red[KSUB][64][BATCH + 1];

    const int tid = threadIdx.x;
    const int ml  = tid & 63;
    const int s   = tid >> 6;
    const int m   = blockIdx.x * 64 + ml;
    const int kc  = blockIdx.y;
    const int k0  = kc * KCH + s * KPT;

    float acc[BATCH];
#pragma unroll
    for (int b = 0; b < BATCH; ++b) acc[b] = 0.0f;

#pragma unroll 4
    for (int k = k0; k < k0 + KPT; ++k) {
        float g = G[(size_t)k * MCOLS + m];
        float c = cn[(size_t)k * MCOLS + m];
        float w = fmaxf(1e-8f, g * (1.0f + 0.1118f * c)) * 0.1f;  // Gn * READ_V
#pragma unroll
        for (int b = 0; b < BATCH; ++b) {
            acc[b] = fmaf(rates[b * NNEUR + k], w, acc[b]);
        }
    }

#pragma unroll
    for (int b = 0; b < BATCH; ++b) red[s][ml][b] = acc[b];
    __syncthreads();

    if (s == 0) {
#pragma unroll
        for (int b = 0; b < BATCH; ++b) {
            float v = ((red[0][ml][b] + red[1][ml][b]) + red[2][ml][b]) + red[3][ml][b];
            part[((size_t)kc * BATCH + b) * MCOLS + m] = v;
        }
    }
}

__global__ __launch_bounds__(256) void readout_reduce_kernel(
    const float* __restrict__ part,
    float* __restrict__ out)
{
    const int i = blockIdx.x * 256 + threadIdx.x;  // 0..8191 = b*512+m
    float s = 0.0f;
#pragma unroll
    for (int kc = 0; kc < KC; ++kc) {
        s += part[kc * (BATCH * MCOLS) + i];
    }
    out[i] = s;
}

extern "C" void kernel_launch(void* const* d_in, const int* in_sizes, int n_in,
                              void* d_out, int out_size, void* d_ws, size_t ws_size,
                              hipStream_t stream)
{
    const float* ext = (const float*)d_in[0];   // [T,B,N]
    const float* inz = (const float*)d_in[1];   // [T,B,N]
    const float* vnz = (const float*)d_in[2];   // [T,B,N]
    const float* G   = (const float*)d_in[3];   // [N,M]
    const float* cn  = (const float*)d_in[4];   // [N,M]
    float* out = (float*)d_out;                 // [B,M] = 8192

    float* rates = (float*)d_ws;                // 32768 floats
    float* part  = rates + BN;                  // 8*16*512 = 65536 floats

    lif_sim_kernel<<<BN / NPB, 256, 0, stream>>>(ext, inz, vnz, rates);
    readout_partial_kernel<<<dim3(MCOLS / 64, KC), 256, 0, stream>>>(rates, G, cn, part);
    readout_reduce_kernel<<<(BATCH * MCOLS) / 256, 256, 0, stream>>>(part, out);
}